// Round 12
// baseline (177.841 us; speedup 1.0000x reference)
//
#include <hip/hip_runtime.h>

// GCN 2-layer forward — R26 = R25 base + fp8(e4m3) h payload for the gather.
// Evidence chain: R21 (instr diet) null, R24 (coalescing) null, R25 (8-deep
// gather + midchain parallelism) null at 172.07 — pullg is FILL-VOLUME
// bound: 12.8MB h table > 4MB/XCD L2, ~68MB compulsory L2-fill per pass
// (R22 FETCH), ~3TB/s fill ~= pullg's whole 29-31us. Only lever left: bytes.
// R26: h stored fp8 e4m3 (table 6.4MB, row=128B=1 line). Encode: RN-even,
// subnorm-correct, clamp 448 (|h|<~5). Decode ~free: as_float((b&0x7f)<<20
// | sign<<24) * 2^120 with 2^120 folded into the edge weight (exact for
// subnorm codes too). gemm1 math (bf16 MFMA) unchanged; pull2/h2 unchanged.
// R13 note: fp8 measured absmax 0.031 < 0.058 threshold (passes; was
// excluded on margin only). Predict total ~158-166, absmax ~0.031.
// Session rules: boundary ~1us (R9); serial global loops poison (R11); bulk
// random atomic scatter poison (R18-rev); gather insensitive to depth/
// instr-count/coalescing (R21/R24/R25) => fill-bound.

typedef unsigned int uint32;
typedef unsigned short u16;
typedef __attribute__((ext_vector_type(8))) short bf16x8;
typedef __attribute__((ext_vector_type(4))) float f32x4;

#define NBMAX 1024
#define CHUNK 2048
#define EH 8192   // edges per hist block

__device__ inline u16 bf16rn(float f) {
    unsigned u = __float_as_uint(f);
    return (u16)((u + 0x7fffu + ((u >> 16) & 1u)) >> 16);
}

// f32 -> fp8 e4m3fn, round-nearest-even, subnormal-correct, clamp to 448.
__device__ inline uint32 fp8e(float f) {
    uint32 u = __float_as_uint(f);
    uint32 s = (u >> 24) & 0x80u;
    uint32 mag = u & 0x7fffffffu;
    if (mag > 0x43E00000u) mag = 0x43E00000u;       // clamp to 448
    int e = (int)(mag >> 23) - 127;
    uint32 m = mag & 0x7fffffu;
    uint32 out = 0;
    if (e >= -6) {                                   // normal e4m3 range
        uint32 mant = m >> 20, rest = m & 0xFFFFFu;
        uint32 rnd = (rest > 0x80000u) || (rest == 0x80000u && (mant & 1u));
        out = (((uint32)(e + 7) << 3) | mant) + rnd; // carry ripples into exp
        if (out > 0x7Eu) out = 0x7Eu;
    } else if (e >= -10) {                           // subnormal (units 2^-9)
        uint32 mf = m | 0x800000u;
        int sh = 14 - e;                             // 21..24
        uint32 mant = mf >> sh;
        uint32 rest = mf & ((1u << sh) - 1u);
        uint32 half = 1u << (sh - 1);
        uint32 rnd = (rest > half) || (rest == half && (mant & 1u));
        out = mant + rnd;                            // carry -> min normal ok
    }
    return s | out;
}

// fp8 byte -> f32 scaled by 2^-120 (caller folds 2^120 into the weight).
__device__ inline float fp8d(uint32 b) {
    return __uint_as_float(((b & 0x7fu) << 20) | ((b & 0x80u) << 24));
}

// ---- L1: gemm1 tiles || hist blocks (LDS hist -> global gh atomics) -------
__global__ __launch_bounds__(256) void k_combo(
    const float* __restrict__ x, const float* __restrict__ W1,
    const int* __restrict__ dstv, int* __restrict__ gh,
    unsigned char* __restrict__ h8, int N, int E, int NB, int ntile)
{
    __shared__ __align__(16) unsigned char smem[128 * 136 * 2];  // 34816 B
    int t = threadIdx.x;

    if ((int)blockIdx.x >= ntile) {
        int* hl = (int*)smem;
        int hb = blockIdx.x - ntile;
        int e0 = hb * EH, e1 = min(e0 + EH, E);
        for (int i = t; i < NB; i += 256) hl[i] = 0;
        __syncthreads();
        for (int e = e0 + t; e < e1; e += 256)
            atomicAdd(&hl[dstv[e] >> 8], 1);
        __syncthreads();
        for (int i = t; i < NB; i += 256) {
            int c = hl[i];
            if (c) atomicAdd(&gh[i], c);   // ~196 device atomics/block (cheap)
        }
        return;
    }

    // gemm1: h[N,128] = x @ W1 (bf16 MFMA, operands swapped: D[feat][node]).
    // Lane owns node=rowbase+ln, features ct*16+quad*4+{0..3}. Output fp8.
    u16* Wl = (u16*)smem;  // [n][k] pitch 136 (2-way bank aliasing: free)
    const float4* Wg4 = (const float4*)W1;
    for (int g = t; g < 128 * 32; g += 256) {
        int k = g >> 5, n4 = (g & 31) * 4;
        float4 v = Wg4[g];
        Wl[(n4 + 0) * 136 + k] = bf16rn(v.x);
        Wl[(n4 + 1) * 136 + k] = bf16rn(v.y);
        Wl[(n4 + 2) * 136 + k] = bf16rn(v.z);
        Wl[(n4 + 3) * 136 + k] = bf16rn(v.w);
    }
    __syncthreads();

    int wave = t >> 6, lane = t & 63;
    int quad = lane >> 4, ln = lane & 15;
    int rowbase = blockIdx.x * 64 + wave * 16;
    int node = rowbase + ln;
    int rclamp = min(node, N - 1);

    f32x4 acc[8];
    #pragma unroll
    for (int ct = 0; ct < 8; ++ct) acc[ct] = (f32x4){0.f, 0.f, 0.f, 0.f};

    #pragma unroll
    for (int q = 0; q < 4; ++q) {
        const float4* xr = (const float4*)(x + (size_t)rclamp * 128 + q * 32 + quad * 8);
        float4 a0 = xr[0], a1 = xr[1];
        bf16x8 xfr;   // B-operand: col=node(ln), k = q*32 + quad*8 + e
        xfr[0] = (short)bf16rn(a0.x); xfr[1] = (short)bf16rn(a0.y);
        xfr[2] = (short)bf16rn(a0.z); xfr[3] = (short)bf16rn(a0.w);
        xfr[4] = (short)bf16rn(a1.x); xfr[5] = (short)bf16rn(a1.y);
        xfr[6] = (short)bf16rn(a1.z); xfr[7] = (short)bf16rn(a1.w);
        #pragma unroll
        for (int ct = 0; ct < 8; ++ct) {
            // A-operand: row=feature-in-block(ln), k = q*32 + quad*8 + e
            bf16x8 wfr = *(const bf16x8*)&Wl[(ct * 16 + ln) * 136 + q * 32 + quad * 8];
            acc[ct] = __builtin_amdgcn_mfma_f32_16x16x32_bf16(wfr, xfr, acc[ct], 0, 0, 0);
        }
    }
    if (node < N) {
        unsigned char* hp = h8 + (size_t)node * 128 + quad * 4;
        #pragma unroll
        for (int ct = 0; ct < 8; ++ct) {
            uint32 p = fp8e(acc[ct][0]) | (fp8e(acc[ct][1]) << 8) |
                       (fp8e(acc[ct][2]) << 16) | (fp8e(acc[ct][3]) << 24);
            *(uint32*)(hp + ct * 16) = p;
        }
    }
}

// ---- L2: exclusive scan of gh via shfl wave-scan (2 barriers) -------------
__global__ __launch_bounds__(1024) void k_scanB(
    const int* __restrict__ gh, int* __restrict__ bbase,
    int* __restrict__ bfill, int NB, int E)
{
    __shared__ int wsum[16];
    int t = threadIdx.x;
    int lane = t & 63, wv = t >> 6;
    int v = (t < NB) ? gh[t] : 0;
    int sc = v;
    #pragma unroll
    for (int off = 1; off < 64; off <<= 1) {
        int u = __shfl_up(sc, off);
        if (lane >= off) sc += u;
    }
    if (lane == 63) wsum[wv] = sc;
    __syncthreads();
    if (wv == 0 && lane < 16) {
        int b = wsum[lane];
        int bs = b;
        #pragma unroll
        for (int off = 1; off < 16; off <<= 1) {
            int u = __shfl_up(bs, off);
            if (lane >= off) bs += u;
        }
        wsum[lane] = bs - b;   // exclusive prefix of wave sums
    }
    __syncthreads();
    int incl = sc + wsum[wv];
    if (t < NB) {
        bbase[t] = incl - v;
        bfill[t] = 0;
    }
    if (t == 0) bbase[NB] = E;
}

// ---- L3: partition edges into bucket regions (512 thr, CHUNK 2048) --------
__global__ __launch_bounds__(512) void k_partition(
    const int* __restrict__ src, const int* __restrict__ dstv,
    const int* __restrict__ bbase, int* __restrict__ bfill,
    uint32* __restrict__ tmp, int E, int NB)
{
    __shared__ int cntL[NBMAX];
    __shared__ int baseL[NBMAX];
    int t = threadIdx.x;
    int e0 = blockIdx.x * CHUNK;
    int e1 = min(e0 + CHUNK, E);
    for (int i = t; i < NB; i += 512) cntL[i] = 0;
    __syncthreads();
    for (int e = e0 + t; e < e1; e += 512)
        atomicAdd(&cntL[dstv[e] >> 8], 1);
    __syncthreads();
    for (int i = t; i < NB; i += 512) {
        int cc = cntL[i];
        baseL[i] = cc ? bbase[i] + atomicAdd(&bfill[i], cc) : 0;
        cntL[i] = 0;
    }
    __syncthreads();
    for (int e = e0 + t; e < e1; e += 512) {
        int sv = src[e], d = dstv[e];
        int b = d >> 8;
        int r = atomicAdd(&cntL[b], 1);
        tmp[baseL[b] + r] = (uint32)sv | ((uint32)(d & 255) << 16);
    }
}

// ---- L4: per-bucket exact sort (1024 threads); emit dinv / rs / ssrc ------
__global__ __launch_bounds__(1024) void k_bsort(
    const uint32* __restrict__ tmp, const int* __restrict__ bbase,
    u16* __restrict__ ssrc, int* __restrict__ rs,
    float* __restrict__ dinv, int N)
{
    __shared__ int cnt[256];
    __shared__ int ofs[256];
    int t = threadIdx.x;
    int b = blockIdx.x;
    int base = bbase[b];
    int endb = bbase[b + 1];
    int node0 = b << 8;

    if (t < 256) cnt[t] = 0;
    __syncthreads();
    for (int i = base + t; i < endb; i += 1024)
        atomicAdd(&cnt[(tmp[i] >> 16) & 255], 1);
    __syncthreads();
    int v = (t < 256) ? cnt[t] : 0;
    __syncthreads();
    for (int off = 1; off < 256; off <<= 1) {
        int u = (t >= off && t < 256) ? cnt[t - off] : 0;
        __syncthreads();
        if (t < 256) cnt[t] += u;
        __syncthreads();
    }
    if (t < 256) {
        int node = node0 + t;
        if (node < N) {
            dinv[node] = rsqrtf(fmaxf((float)v, 1.0f));
            rs[node] = base + cnt[t];
        }
        ofs[t] = base + cnt[t] - v;
    }
    __syncthreads();
    for (int i = base + t; i < endb; i += 1024) {
        uint32 rec = tmp[i];
        int pos = atomicAdd(&ofs[(rec >> 16) & 255], 1);
        ssrc[pos] = (u16)(rec & 0xffffu);
    }
}

// ---- L5: pullg — fused pull1 + gemm2; fp8 gather --------------------------
__global__ __launch_bounds__(256) void k_pullg(
    const int* __restrict__ rs, const u16* __restrict__ ssrc,
    const float* __restrict__ dinv, const uint32* __restrict__ h8,
    const float* __restrict__ b1, const float* __restrict__ W2,
    u16* __restrict__ h2, int N)
{
    __shared__ float W2T[16 * 132];   // [f][k] pitch 132
    __shared__ float rowbuf[8 * 132]; // [r][k] pitch 132 (float4 pitch 33)
    int t = threadIdx.x;

    for (int g = t; g < 2048; g += 256) {
        int k = g >> 4, f = g & 15;
        W2T[f * 132 + k] = W2[g];
    }

    int wave = t >> 6, lane = t & 63;
    int sub = lane >> 5;
    int rl = lane & 31;                // lane's 4 features = 4*rl..4*rl+3
    int rowbase = blockIdx.x * 8;
    int n = rowbase + wave * 2 + sub;
    bool valid = (n < N);
    int nc = valid ? n : 0;
    int start = valid ? ((nc == 0) ? 0 : rs[nc - 1]) : 0;
    int len   = valid ? (rs[nc] - start) : 0;
    float dn  = valid ? dinv[nc] : 0.f;
    int lenMax = max(len, __shfl_xor(len, 32));

    float4 av[4];
    #pragma unroll
    for (int k = 0; k < 4; ++k) av[k] = (float4){0.f, 0.f, 0.f, 0.f};

    for (int tt = 0; tt < lenMax; tt += 8) {
        int s[8];
        uint32 u[8];
        float w[8];
        #pragma unroll
        for (int k = 0; k < 8; ++k) {
            bool act = (tt + k) < len;
            int jj = act ? (start + tt + k) : 0;   // index 0 always valid
            s[k] = (int)ssrc[jj];
            w[k] = act ? 0x1p120f : 0.f;           // fold fp8 2^120 rebias
        }
        #pragma unroll
        for (int k = 0; k < 8; ++k)
            u[k] = h8[(size_t)s[k] * 32 + rl];     // 128B row, coalesced
        #pragma unroll
        for (int k = 0; k < 8; ++k)
            w[k] *= dinv[s[k]];                    // dn folded to epilogue
        #pragma unroll
        for (int k = 0; k < 8; ++k) {
            float4& a = av[k & 3];
            uint32 b = u[k];
            a.x = fmaf(w[k], fp8d(b), a.x);
            a.y = fmaf(w[k], fp8d(b >> 8), a.y);
            a.z = fmaf(w[k], fp8d(b >> 16), a.z);
            a.w = fmaf(w[k], fp8d(b >> 24), a.w);
        }
    }

    {
        int r = wave * 2 + sub;
        float4 bb = ((const float4*)b1)[rl];
        float4 v;
        v.x = fmaxf(fmaf(dn, (av[0].x + av[1].x) + (av[2].x + av[3].x), bb.x), 0.f);
        v.y = fmaxf(fmaf(dn, (av[0].y + av[1].y) + (av[2].y + av[3].y), bb.y), 0.f);
        v.z = fmaxf(fmaf(dn, (av[0].z + av[1].z) + (av[2].z + av[3].z), bb.z), 0.f);
        v.w = fmaxf(fmaf(dn, (av[0].w + av[1].w) + (av[2].w + av[3].w), bb.w), 0.f);
        ((float4*)rowbuf)[r * 33 + rl] = v;
    }
    __syncthreads();

    if (t < 128) {
        int f = t & 15, r = t >> 4;
        const float4* W4 = (const float4*)W2T;
        const float4* rb4 = (const float4*)rowbuf;
        float acc = 0.f;
        #pragma unroll 8
        for (int k4 = 0; k4 < 32; ++k4) {
            float4 w = W4[f * 33 + k4];
            float4 xv = rb4[r * 33 + k4];
            acc = fmaf(xv.x, w.x, acc);
            acc = fmaf(xv.y, w.y, acc);
            acc = fmaf(xv.z, w.z, acc);
            acc = fmaf(xv.w, w.w, acc);
        }
        int rn = rowbase + r;
        if (rn < N) h2[(size_t)rn * 16 + f] = bf16rn(acc);
    }
}

// ---- L6: pull2 + log_softmax, 4-deep unroll -------------------------------
__global__ __launch_bounds__(256) void k_pull2(
    const int* __restrict__ rs, const u16* __restrict__ ssrc,
    const float* __restrict__ dinv, const uint32* __restrict__ h2,
    const float* __restrict__ b2, float* __restrict__ out, int N)
{
    int idx = blockIdx.x * 256 + threadIdx.x;
    int n = idx >> 3;
    if (n >= N) return;
    int c = idx & 7;
    int start = (n == 0) ? 0 : rs[n - 1];
    int len = rs[n] - start;
    float dn = dinv[n];

    float2 a[4];
    #pragma unroll
    for (int k = 0; k < 4; ++k) a[k] = (float2){0.f, 0.f};

    for (int tt = 0; tt < len; tt += 4) {
        int s[4];
        uint32 u[4];
        float w[4];
        #pragma unroll
        for (int k = 0; k < 4; ++k) {
            bool act = (tt + k) < len;
            int jj = act ? (start + tt + k) : 0;   // index 0 always valid
            s[k] = (int)ssrc[jj];
            w[k] = act ? 1.f : 0.f;
        }
        #pragma unroll
        for (int k = 0; k < 4; ++k)
            u[k] = h2[(size_t)s[k] * 8 + c];
        #pragma unroll
        for (int k = 0; k < 4; ++k)
            w[k] *= dn * dinv[s[k]];
        #pragma unroll
        for (int k = 0; k < 4; ++k) {
            a[k].x = fmaf(w[k], __uint_as_float(u[k] << 16), a[k].x);
            a[k].y = fmaf(w[k], __uint_as_float(u[k] & 0xffff0000u), a[k].y);
        }
    }

    float acc0 = (a[0].x + a[1].x) + (a[2].x + a[3].x);
    float acc1 = (a[0].y + a[1].y) + (a[2].y + a[3].y);
    float v0 = acc0 + b2[2 * c];
    float v1 = acc1 + b2[2 * c + 1];
    float m = fmaxf(v0, v1);
    #pragma unroll
    for (int off = 1; off < 8; off <<= 1) m = fmaxf(m, __shfl_xor(m, off));
    float s = expf(v0 - m) + expf(v1 - m);
    #pragma unroll
    for (int off = 1; off < 8; off <<= 1) s += __shfl_xor(s, off);
    float ls = logf(s);
    float2 r = {v0 - m - ls, v1 - m - ls};
    ((float2*)out)[(size_t)n * 8 + c] = r;
}

extern "C" void kernel_launch(void* const* d_in, const int* in_sizes, int n_in,
                              void* d_out, int out_size, void* d_ws, size_t ws_size,
                              hipStream_t stream) {
    const float* x  = (const float*)d_in[0];
    const int*   ei = (const int*)d_in[1];
    const float* W1 = (const float*)d_in[2];
    const float* b1 = (const float*)d_in[3];
    const float* W2 = (const float*)d_in[4];
    const float* b2 = (const float*)d_in[5];
    float* outp = (float*)d_out;

    const int E = in_sizes[1] / 2;
    const int N = in_sizes[0] / 128;   // N=50000 (fits u16 src packing)
    const int NB = (N + 255) >> 8;
    const int NH = (E + EH - 1) / EH;
    const int ntile = (N + 63) / 64;
    const int* src  = ei;
    const int* dstv = ei + E;

    const int Npad = (N + 255) & ~255;
    const int Epad = (E + 255) & ~255;
    int*   gh    = (int*)d_ws;                      // [NBMAX] global hist
    int*   bbase = gh + NBMAX;                      // [NBMAX+1] (+pad)
    int*   bfill = bbase + NBMAX + 256;             // [NBMAX]
    int*   rs    = bfill + NBMAX;                   // [Npad]
    float* dinv  = (float*)(rs + Npad);             // [Npad]
    uint32* tmp  = (uint32*)(dinv + Npad);          // [Epad] packed src|dstlow
    u16*   ssrc  = (u16*)(tmp + Epad);              // [Epad] u16
    uintptr_t hp = ((uintptr_t)(ssrc + Epad) + 255) & ~(uintptr_t)255;
    unsigned char* h8 = (unsigned char*)hp;         // [Npad*128] fp8 e4m3
    u16*   h2    = (u16*)(h8 + (size_t)Npad * 128); // [Npad*16] bf16

    hipMemsetAsync(gh, 0, NBMAX * sizeof(int), stream);
    k_combo<<<ntile + NH, 256, 0, stream>>>(x, W1, dstv, gh, h8, N, E, NB, ntile);
    k_scanB<<<1, 1024, 0, stream>>>(gh, bbase, bfill, NB, E);
    k_partition<<<(E + CHUNK - 1) / CHUNK, 512, 0, stream>>>(src, dstv, bbase,
                                                             bfill, tmp, E, NB);
    k_bsort<<<NB, 1024, 0, stream>>>(tmp, bbase, ssrc, rs, dinv, N);
    k_pullg<<<(N + 7) / 8, 256, 0, stream>>>(rs, ssrc, dinv, (const uint32*)h8,
                                             b1, W2, h2, N);
    k_pull2<<<(N * 8 + 255) / 256, 256, 0, stream>>>(rs, ssrc, dinv,
                                                     (const uint32*)h2, b2, outp, N);
}